// Round 5
// baseline (493.010 us; speedup 1.0000x reference)
//
#include <hip/hip_runtime.h>
#include <math.h>

// Problem constants
// x: (B=2, C=32, D=96, H=96, W=96) fp32
// out: (2, 32, 48, 48, 48) fp32
#define HS 0.35355339059327373f   /* 1/(2*sqrt(2)) — 3-stage Haar scale */
#define NSPAT 110592              /* 48^3 */
#define NBN   221184              /* B * 48^3 */

// ---------------------------------------------------------------------------
// K1: per-(b,c) parity sums S[b][c][p][q][r] = sum over x[2i+p][2j+q][2l+r]
// One block per (b,c,d)-plane: 96*96 floats = 2304 float4s, 256 thr * 9.
// Memory-bound (226 MB @ ~6 TB/s ≈ 40 µs).
// ---------------------------------------------------------------------------
__global__ __launch_bounds__(256) void k1_parity(const float* __restrict__ x,
                                                 float* __restrict__ S) {
    int blk = blockIdx.x;            // (b*32+c)*96 + d
    int d   = blk % 96;
    int bc  = blk / 96;
    const float4* x4 = (const float4*)x + (long)blk * 2304;
    int tid = threadIdx.x;
    float aE0 = 0.f, aO0 = 0.f, aE1 = 0.f, aO1 = 0.f;  // [q][r]
#pragma unroll
    for (int i = 0; i < 9; ++i) {
        int f = tid + i * 256;           // < 2304
        float4 v = x4[f];
        int h = f / 24;                  // row within plane
        float e = v.x + v.z, o = v.y + v.w;
        if (h & 1) { aE1 += e; aO1 += o; }
        else       { aE0 += e; aO0 += o; }
    }
#pragma unroll
    for (int m = 32; m; m >>= 1) {
        aE0 += __shfl_xor(aE0, m, 64); aO0 += __shfl_xor(aO0, m, 64);
        aE1 += __shfl_xor(aE1, m, 64); aO1 += __shfl_xor(aO1, m, 64);
    }
    __shared__ float red[4][4];
    int lane = tid & 63, wave = tid >> 6;
    if (lane == 0) { red[wave][0] = aE0; red[wave][1] = aO0;
                     red[wave][2] = aE1; red[wave][3] = aO1; }
    __syncthreads();
    if (tid < 4) {
        float v = red[0][tid] + red[1][tid] + red[2][tid] + red[3][tid];
        int q = tid >> 1, r = tid & 1, p = d & 1;
        atomicAdd(&S[bc * 8 + p * 4 + q * 2 + r], v);
    }
}

// ---------------------------------------------------------------------------
// K2 (tiny): band means -> two attention MLPs -> effective fuse matrix.
// R5 layout: A[b][c][o][pqr] — per-c slice is 256 contiguous floats so k3's
// wave-uniform c-iteration reads contiguous s_load_dwordx16 batches.
// One block per batch b.
// ---------------------------------------------------------------------------
__global__ __launch_bounds__(256) void k2_attn(
        const float* __restrict__ S,
        const float* __restrict__ w1l, const float* __restrict__ w2l,
        const float* __restrict__ w1h, const float* __restrict__ w2h,
        const float* __restrict__ wf, float* __restrict__ A) {
    int b = blockIdx.x, tid = threadIdx.x;
    __shared__ float mlow[32], mhigh[224], h1l[2], h1h[14], ylow[32], yhigh[224];
    const float* Sb = S + b * 256;
    const float MS = HS / (float)NSPAT;   // subband mean scale
    if (tid < 32) {
        float s = 0.f;
        for (int j = 0; j < 8; ++j) s += Sb[tid * 8 + j];
        mlow[tid] = s * MS;
    }
    if (tid < 224) {
        int c = tid / 7, k = tid % 7, dm = k + 1;
        float s = 0.f;
        for (int j = 0; j < 8; ++j) {
            float sg = (__popc(j & dm) & 1) ? -1.f : 1.f;
            s += sg * Sb[c * 8 + j];
        }
        mhigh[tid] = s * MS;
    }
    __syncthreads();
    if (tid < 2) {
        float s = 0.f;
        for (int c = 0; c < 32; ++c) s += w1l[tid * 32 + c] * mlow[c];
        h1l[tid] = fmaxf(s, 0.f);
    } else if (tid < 16) {
        int j = tid - 2;
        float s = 0.f;
        for (int c = 0; c < 224; ++c) s += w1h[j * 224 + c] * mhigh[c];
        h1h[j] = fmaxf(s, 0.f);
    }
    __syncthreads();
    if (tid < 32) {
        float s = w2l[tid * 2] * h1l[0] + w2l[tid * 2 + 1] * h1l[1];
        ylow[tid] = 1.f / (1.f + expf(-s));
    } else if (tid < 256) {
        int i = tid - 32;
        float s = 0.f;
        for (int j = 0; j < 14; ++j) s += w2h[i * 14 + j] * h1h[j];
        yhigh[i] = 1.f / (1.f + expf(-s));
    }
    __syncthreads();
    for (int idx = tid; idx < 8192; idx += 256) {
        int o = idx >> 8, c = (idx >> 3) & 31, pqr = idx & 7;
        float a = wf[o * 256 + c] * ylow[c];
#pragma unroll
        for (int k = 0; k < 7; ++k) {
            float sg = (__popc(pqr & (k + 1)) & 1) ? -1.f : 1.f;
            a += sg * wf[o * 256 + 32 + c * 7 + k] * yhigh[c * 7 + k];
        }
        A[b * 8192 + c * 256 + o * 8 + pqr] = a * HS;   // [b][c][o][pqr]
    }
}

// ---------------------------------------------------------------------------
// K3 (main): z[b,o,od,oh,ow] = sum_{c,pqr} A[b,c,o,pqr] * x[b,c,2od+p,2oh+q,2ow+r]
// R5: x read ONCE (226 MB). K-split across the 4 waves of a block:
// wave w owns c in [8w, 8w+8); each thread handles ONE output voxel for ALL
// 32 o (32 acc VGPRs, ~70 total -> ~7 waves/SIMD resident). A address is
// wave-uniform (readfirstlane) -> scalar-pipe s_loads, free v_fma operand.
// Partials cross-wave-reduced via 33-padded LDS (2-way aliasing = free),
// transposed so z stores are 2x float4 fully coalesced per o.
// Grid 3456 = b(2) x od(48) x vblk(36); block 256 = 4 waves x 64 voxels.
// BN atomics spread over 16 replica lines to kill same-address contention.
// ---------------------------------------------------------------------------
__global__ __launch_bounds__(256) void k3_main(const float* __restrict__ x,
                                               const float* __restrict__ A,
                                               float* __restrict__ z,
                                               float* __restrict__ bnRep) {
    __shared__ float lds[4 * 64 * 33];     // [wave][voxel][o] pad 33
    int blk  = blockIdx.x;                 // (b*48+od)*36 + vblk
    int vblk = blk % 36;
    int tmp  = blk / 36;
    int od   = tmp % 48;
    int b    = tmp / 48;
    int tid  = threadIdx.x;
    int lane = tid & 63;
    int wv   = __builtin_amdgcn_readfirstlane(tid >> 6);  // c-quarter, scalar
    int vbase = vblk * 64;
    int v    = vbase + lane;
    int oh   = v / 48, ow = v % 48;

    const float* Ab = A + b * 8192;

    float acc[32];
#pragma unroll
    for (int o = 0; o < 32; ++o) acc[o] = 0.f;

    const float2* x2 = (const float2*)x;
    // float2 idx: ch*442368 + d*4608 + h*48 + ow ; d=2od(+p), h=2oh(+q)
    int base = (b * 32 + wv * 8) * 442368 + od * 9216 + oh * 96 + ow;

    float2 v00 = x2[base], v01 = x2[base + 48];
    float2 v10 = x2[base + 4608], v11 = x2[base + 4656];
#pragma unroll
    for (int i = 0; i < 8; ++i) {
        float2 n00, n01, n10, n11;
        if (i < 7) {
            int nb = base + (i + 1) * 442368;
            n00 = x2[nb]; n01 = x2[nb + 48];
            n10 = x2[nb + 4608]; n11 = x2[nb + 4656];
        }
        const float* Ac = Ab + (wv * 8 + i) * 256;   // uniform -> SGPRs
#pragma unroll
        for (int o = 0; o < 32; ++o) {
            const float* Ao = Ac + o * 8;
            acc[o] += Ao[0] * v00.x + Ao[1] * v00.y + Ao[2] * v01.x + Ao[3] * v01.y
                    + Ao[4] * v10.x + Ao[5] * v10.y + Ao[6] * v11.x + Ao[7] * v11.y;
        }
        if (i < 7) { v00 = n00; v01 = n01; v10 = n10; v11 = n11; }
    }

    // dump partials: lds[wv][lane][o]; b128 writes, (l*33+o)%32 -> 2-way = free
    float* mine = &lds[(wv * 64 + lane) * 33];
#pragma unroll
    for (int o = 0; o < 32; ++o) mine[o] = acc[o];
    __syncthreads();

    // reduce + transpose: thread -> o = tid>>3, voxel group g = tid&7
    int o = tid >> 3, g = tid & 7;
    float val[8];
#pragma unroll
    for (int j = 0; j < 8; ++j) {
        int a0 = (g * 8 + j) * 33 + o;
        val[j] = lds[a0] + lds[2112 + a0] + lds[4224 + a0] + lds[6336 + a0];
    }
    // z store: 8 consecutive voxels of channel o -> 2 coalesced float4
    int zf = ((b * 32 + o) * 48 + od) * 2304 + vbase + g * 8;
    float4* z4 = (float4*)(z + zf);
    z4[0] = make_float4(val[0], val[1], val[2], val[3]);
    z4[1] = make_float4(val[4], val[5], val[6], val[7]);

    // BN partial sums: reduce over the 8 lanes sharing this o
    float sv = 0.f, qv = 0.f;
#pragma unroll
    for (int j = 0; j < 8; ++j) { sv += val[j]; qv += val[j] * val[j]; }
#pragma unroll
    for (int m = 1; m <= 4; m <<= 1) {
        sv += __shfl_xor(sv, m, 64);
        qv += __shfl_xor(qv, m, 64);
    }
    if ((tid & 7) == 0) {
        int rep = (blockIdx.x & 15) * 64;
        atomicAdd(&bnRep[rep + o], sv);
        atomicAdd(&bnRep[rep + 32 + o], qv);
    }
}

// ---------------------------------------------------------------------------
// K5: BN finalize (sum 16 replicas, per-block recompute) + normalize + ReLU,
// in place over z (= d_out). 1769472 float4s. b_fuse cancels under BN.
// ---------------------------------------------------------------------------
__global__ __launch_bounds__(256) void k5_norm(float* __restrict__ z,
                                               const float* __restrict__ bnRep,
                                               const float* __restrict__ gamma,
                                               const float* __restrict__ beta) {
    __shared__ float s_sc[32], s_sh[32];
    int tid = threadIdx.x;
    if (tid < 32) {
        float s = 0.f, q = 0.f;
#pragma unroll
        for (int r = 0; r < 16; ++r) {
            s += bnRep[r * 64 + tid];
            q += bnRep[r * 64 + 32 + tid];
        }
        const float invN = 1.f / (float)NBN;
        float mean = s * invN;
        float var  = q * invN - mean * mean;
        float inv  = rsqrtf(var + 1e-5f);
        float sc   = gamma[tid] * inv;
        s_sc[tid] = sc;
        s_sh[tid] = beta[tid] - mean * sc;
    }
    int i = blockIdx.x * 256 + tid;                // float4 index
    float4* z4 = (float4*)z;
    float4 v = z4[i];                              // load before barrier (indep)
    __syncthreads();
    int o = (i / 27648) & 31;                      // 27648 = 48^3/4
    float sc = s_sc[o], sh = s_sh[o];
    v.x = fmaxf(v.x * sc + sh, 0.f);
    v.y = fmaxf(v.y * sc + sh, 0.f);
    v.z = fmaxf(v.z * sc + sh, 0.f);
    v.w = fmaxf(v.w * sc + sh, 0.f);
    z4[i] = v;
}

extern "C" void kernel_launch(void* const* d_in, const int* in_sizes, int n_in,
                              void* d_out, int out_size, void* d_ws, size_t ws_size,
                              hipStream_t stream) {
    const float* x    = (const float*)d_in[0];
    const float* w1l  = (const float*)d_in[1];
    const float* w2l  = (const float*)d_in[2];
    const float* w1h  = (const float*)d_in[3];
    const float* w2h  = (const float*)d_in[4];
    const float* wf   = (const float*)d_in[5];
    // d_in[6] = b_fuse: cancels exactly under training-mode BN (mean subtract)
    const float* gamma = (const float*)d_in[7];
    const float* beta  = (const float*)d_in[8];
    float* out = (float*)d_out;

    float* ws    = (float*)d_ws;
    float* S     = ws;          // 512 floats (zeroed)
    float* bnRep = ws + 512;    // 16 x (32 sum + 32 sq) = 1024 floats (zeroed)
    float* A     = ws + 2048;   // 16384 floats

    hipMemsetAsync(d_ws, 0, 1536 * sizeof(float), stream);
    k1_parity<<<6144, 256, 0, stream>>>(x, S);
    k2_attn<<<2, 256, 0, stream>>>(S, w1l, w2l, w1h, w2h, wf, A);
    k3_main<<<3456, 256, 0, stream>>>(x, A, out, bnRep);
    k5_norm<<<6912, 256, 0, stream>>>(out, bnRep, gamma, beta);
}

// Round 6
// 480.940 us; speedup vs baseline: 1.0251x; 1.0251x over previous
//
#include <hip/hip_runtime.h>
#include <math.h>

// Problem constants
// x: (B=2, C=32, D=96, H=96, W=96) fp32
// out: (2, 32, 48, 48, 48) fp32
#define HS 0.35355339059327373f   /* 1/(2*sqrt(2)) — 3-stage Haar scale */
#define NSPAT 110592              /* 48^3 */
#define NBN   221184              /* B * 48^3 */

// ---------------------------------------------------------------------------
// K1: per-(b,c) parity sums S[b][c][p][q][r] = sum over x[2i+p][2j+q][2l+r]
// One block per (b,c,d)-plane: 96*96 floats = 2304 float4s, 256 thr * 9.
// Memory-bound (226 MB @ ~5.6 TB/s ≈ 40 µs) — near floor.
// ---------------------------------------------------------------------------
__global__ __launch_bounds__(256) void k1_parity(const float* __restrict__ x,
                                                 float* __restrict__ S) {
    int blk = blockIdx.x;            // (b*32+c)*96 + d
    int d   = blk % 96;
    int bc  = blk / 96;
    const float4* x4 = (const float4*)x + (long)blk * 2304;
    int tid = threadIdx.x;
    float aE0 = 0.f, aO0 = 0.f, aE1 = 0.f, aO1 = 0.f;  // [q][r]
#pragma unroll
    for (int i = 0; i < 9; ++i) {
        int f = tid + i * 256;           // < 2304
        float4 v = x4[f];
        int h = f / 24;                  // row within plane
        float e = v.x + v.z, o = v.y + v.w;
        if (h & 1) { aE1 += e; aO1 += o; }
        else       { aE0 += e; aO0 += o; }
    }
#pragma unroll
    for (int m = 32; m; m >>= 1) {
        aE0 += __shfl_xor(aE0, m, 64); aO0 += __shfl_xor(aO0, m, 64);
        aE1 += __shfl_xor(aE1, m, 64); aO1 += __shfl_xor(aO1, m, 64);
    }
    __shared__ float red[4][4];
    int lane = tid & 63, wave = tid >> 6;
    if (lane == 0) { red[wave][0] = aE0; red[wave][1] = aO0;
                     red[wave][2] = aE1; red[wave][3] = aO1; }
    __syncthreads();
    if (tid < 4) {
        float v = red[0][tid] + red[1][tid] + red[2][tid] + red[3][tid];
        int q = tid >> 1, r = tid & 1, p = d & 1;
        atomicAdd(&S[bc * 8 + p * 4 + q * 2 + r], v);
    }
}

// ---------------------------------------------------------------------------
// K2 (tiny): band means -> two attention MLPs -> effective fuse matrix.
// R6 layout: A[b][og(4)][c(32)][o'(8)][pqr(8)] — per-(og,c) slice is 64
// contiguous floats (fits SGPRs single-buffered in k3's c-loop).
// One block per batch b.
// ---------------------------------------------------------------------------
__global__ __launch_bounds__(256) void k2_attn(
        const float* __restrict__ S,
        const float* __restrict__ w1l, const float* __restrict__ w2l,
        const float* __restrict__ w1h, const float* __restrict__ w2h,
        const float* __restrict__ wf, float* __restrict__ A) {
    int b = blockIdx.x, tid = threadIdx.x;
    __shared__ float mlow[32], mhigh[224], h1l[2], h1h[14], ylow[32], yhigh[224];
    const float* Sb = S + b * 256;
    const float MS = HS / (float)NSPAT;   // subband mean scale
    if (tid < 32) {
        float s = 0.f;
        for (int j = 0; j < 8; ++j) s += Sb[tid * 8 + j];
        mlow[tid] = s * MS;
    }
    if (tid < 224) {
        int c = tid / 7, k = tid % 7, dm = k + 1;
        float s = 0.f;
        for (int j = 0; j < 8; ++j) {
            float sg = (__popc(j & dm) & 1) ? -1.f : 1.f;
            s += sg * Sb[c * 8 + j];
        }
        mhigh[tid] = s * MS;
    }
    __syncthreads();
    if (tid < 2) {
        float s = 0.f;
        for (int c = 0; c < 32; ++c) s += w1l[tid * 32 + c] * mlow[c];
        h1l[tid] = fmaxf(s, 0.f);
    } else if (tid < 16) {
        int j = tid - 2;
        float s = 0.f;
        for (int c = 0; c < 224; ++c) s += w1h[j * 224 + c] * mhigh[c];
        h1h[j] = fmaxf(s, 0.f);
    }
    __syncthreads();
    if (tid < 32) {
        float s = w2l[tid * 2] * h1l[0] + w2l[tid * 2 + 1] * h1l[1];
        ylow[tid] = 1.f / (1.f + expf(-s));
    } else if (tid < 256) {
        int i = tid - 32;
        float s = 0.f;
        for (int j = 0; j < 14; ++j) s += w2h[i * 14 + j] * h1h[j];
        yhigh[i] = 1.f / (1.f + expf(-s));
    }
    __syncthreads();
    for (int idx = tid; idx < 8192; idx += 256) {
        int o = idx >> 8, c = (idx >> 3) & 31, pqr = idx & 7;
        float a = wf[o * 256 + c] * ylow[c];
#pragma unroll
        for (int k = 0; k < 7; ++k) {
            float sg = (__popc(pqr & (k + 1)) & 1) ? -1.f : 1.f;
            a += sg * wf[o * 256 + 32 + c * 7 + k] * yhigh[c * 7 + k];
        }
        int og = o >> 3, op = o & 7;
        A[b * 8192 + og * 2048 + c * 64 + op * 8 + pqr] = a * HS;
    }
}

// ---------------------------------------------------------------------------
// K3 (main): z[b,o,od,oh,ow] = sum_{c,pqr} A[...] * x[b,c,2od+p,2oh+q,2ow+r]
// R6: (N_o=8 outputs, N_v=4 voxels) per thread — the reuse sweet spot:
//  - FMA per A-float = 4 (R3 had 2, R5 had 1): per c-iter A = 64 contiguous
//    floats (k2 layout) = 64 SGPRs, block-uniform -> scalar pipe; 256 FMA
//    insts per c-iter hide the s_load chunk waits.
//  - FMA per x-float = 8; x logical 906 MB but LLC-resident after k1
//    (R4/R5 measured FETCH ~112 MB), so no HBM penalty.
//  - Stores: 4 consecutive ow per thread -> one coalesced float4 per o.
//    No LDS transpose epilogue (R5's 885K bank-conflict cycles deleted).
// Grid 1152 = b(2) x od(48) x ohg(3) x og(4), og fastest -> the 4 og-siblings
// run concurrently (LLC timing locality). Block 192 = 16 oh-rows x 12 t.
// 3456 waves = 3.375/SIMD; VGPR ~110 (32 acc + 32 cur + 32 next x + addr).
// ---------------------------------------------------------------------------
__global__ __launch_bounds__(192) void k3_main(const float* __restrict__ x,
                                               const float* __restrict__ A,
                                               float* __restrict__ z,
                                               float* __restrict__ bnRep) {
    __shared__ float red[3][16];
    int blk = blockIdx.x;              // (((b*48+od)*3+ohg)*4)+og
    int og  = blk & 3;
    int rem = blk >> 2;
    int ohg = rem % 3;
    int tmp = rem / 3;
    int od  = tmp % 48;
    int b   = tmp / 48;
    int tid = threadIdx.x;
    int row = tid / 12;                // 0..15
    int t   = tid % 12;                // ow group: outputs 4t..4t+3
    int oh  = ohg * 16 + row;

    const float* Ab = A + b * 8192 + og * 2048;  // [c<32][o'<8][pqr<8], uniform

    float acc0[8], acc1[8], acc2[8], acc3[8];    // [o][voxel]
#pragma unroll
    for (int o = 0; o < 8; ++o) { acc0[o] = 0.f; acc1[o] = 0.f;
                                  acc2[o] = 0.f; acc3[o] = 0.f; }

    const float4* x4 = (const float4*)x;
    // float4 idx: ch*221184 + d*2304 + h*24 + (2t + {0,1}); d=2od+p, h=2oh+q
    int base = (b * 32) * 221184 + (2 * od) * 2304 + (2 * oh) * 24 + 2 * t;

    float4 u00a = x4[base],        u00b = x4[base + 1];
    float4 u01a = x4[base + 24],   u01b = x4[base + 25];
    float4 u10a = x4[base + 2304], u10b = x4[base + 2305];
    float4 u11a = x4[base + 2328], u11b = x4[base + 2329];
    for (int c = 0; c < 32; ++c) {
        float4 n00a, n00b, n01a, n01b, n10a, n10b, n11a, n11b;
        if (c < 31) {
            int i4 = base + (c + 1) * 221184;
            n00a = x4[i4];        n00b = x4[i4 + 1];
            n01a = x4[i4 + 24];   n01b = x4[i4 + 25];
            n10a = x4[i4 + 2304]; n10b = x4[i4 + 2305];
            n11a = x4[i4 + 2328]; n11b = x4[i4 + 2329];
        }
        const float* Ac = Ab + c * 64;
#pragma unroll
        for (int o = 0; o < 8; ++o) {
            const float* Ao = Ac + o * 8;       // uniform -> SGPRs
            float a0 = Ao[0], a1 = Ao[1], a2 = Ao[2], a3 = Ao[3];
            float a4 = Ao[4], a5 = Ao[5], a6 = Ao[6], a7 = Ao[7];
            acc0[o] += a0 * u00a.x + a1 * u00a.y + a2 * u01a.x + a3 * u01a.y
                     + a4 * u10a.x + a5 * u10a.y + a6 * u11a.x + a7 * u11a.y;
            acc1[o] += a0 * u00a.z + a1 * u00a.w + a2 * u01a.z + a3 * u01a.w
                     + a4 * u10a.z + a5 * u10a.w + a6 * u11a.z + a7 * u11a.w;
            acc2[o] += a0 * u00b.x + a1 * u00b.y + a2 * u01b.x + a3 * u01b.y
                     + a4 * u10b.x + a5 * u10b.y + a6 * u11b.x + a7 * u11b.y;
            acc3[o] += a0 * u00b.z + a1 * u00b.w + a2 * u01b.z + a3 * u01b.w
                     + a4 * u10b.z + a5 * u10b.w + a6 * u11b.z + a7 * u11b.w;
        }
        u00a = n00a; u00b = n00b; u01a = n01a; u01b = n01b;
        u10a = n10a; u10b = n10b; u11a = n11a; u11b = n11b;
    }

    // z stores: one float4 per o, consecutive t -> consecutive float4s
    float4* z4 = (float4*)z;
#pragma unroll
    for (int o = 0; o < 8; ++o) {
        int zf = (((b * 32 + og * 8 + o) * 48 + od) * 48 + oh) * 12 + t;
        z4[zf] = make_float4(acc0[o], acc1[o], acc2[o], acc3[o]);
    }

    // BN partial sums for this block's 8 channels
    int lane = tid & 63, wave = tid >> 6;
#pragma unroll
    for (int o = 0; o < 8; ++o) {
        float sv = acc0[o] + acc1[o] + acc2[o] + acc3[o];
        float qv = acc0[o] * acc0[o] + acc1[o] * acc1[o]
                 + acc2[o] * acc2[o] + acc3[o] * acc3[o];
#pragma unroll
        for (int m = 32; m; m >>= 1) {
            sv += __shfl_xor(sv, m, 64);
            qv += __shfl_xor(qv, m, 64);
        }
        if (lane == 0) { red[wave][o] = sv; red[wave][8 + o] = qv; }
    }
    __syncthreads();
    if (tid < 16) {
        float v = red[0][tid] + red[1][tid] + red[2][tid];
        int rep = (blockIdx.x & 15) * 64;
        if (tid < 8) atomicAdd(&bnRep[rep + og * 8 + tid], v);
        else         atomicAdd(&bnRep[rep + 32 + og * 8 + tid - 8], v);
    }
}

// ---------------------------------------------------------------------------
// K5: BN finalize (sum 16 replicas, per-block recompute) + normalize + ReLU,
// in place over z (= d_out). 1769472 float4s. b_fuse cancels under BN.
// ---------------------------------------------------------------------------
__global__ __launch_bounds__(256) void k5_norm(float* __restrict__ z,
                                               const float* __restrict__ bnRep,
                                               const float* __restrict__ gamma,
                                               const float* __restrict__ beta) {
    __shared__ float s_sc[32], s_sh[32];
    int tid = threadIdx.x;
    if (tid < 32) {
        float s = 0.f, q = 0.f;
#pragma unroll
        for (int r = 0; r < 16; ++r) {
            s += bnRep[r * 64 + tid];
            q += bnRep[r * 64 + 32 + tid];
        }
        const float invN = 1.f / (float)NBN;
        float mean = s * invN;
        float var  = q * invN - mean * mean;
        float inv  = rsqrtf(var + 1e-5f);
        float sc   = gamma[tid] * inv;
        s_sc[tid] = sc;
        s_sh[tid] = beta[tid] - mean * sc;
    }
    int i = blockIdx.x * 256 + tid;                // float4 index
    float4* z4 = (float4*)z;
    float4 v = z4[i];                              // load before barrier (indep)
    __syncthreads();
    int o = (i / 27648) & 31;                      // 27648 = 48^3/4
    float sc = s_sc[o], sh = s_sh[o];
    v.x = fmaxf(v.x * sc + sh, 0.f);
    v.y = fmaxf(v.y * sc + sh, 0.f);
    v.z = fmaxf(v.z * sc + sh, 0.f);
    v.w = fmaxf(v.w * sc + sh, 0.f);
    z4[i] = v;
}

extern "C" void kernel_launch(void* const* d_in, const int* in_sizes, int n_in,
                              void* d_out, int out_size, void* d_ws, size_t ws_size,
                              hipStream_t stream) {
    const float* x    = (const float*)d_in[0];
    const float* w1l  = (const float*)d_in[1];
    const float* w2l  = (const float*)d_in[2];
    const float* w1h  = (const float*)d_in[3];
    const float* w2h  = (const float*)d_in[4];
    const float* wf   = (const float*)d_in[5];
    // d_in[6] = b_fuse: cancels exactly under training-mode BN (mean subtract)
    const float* gamma = (const float*)d_in[7];
    const float* beta  = (const float*)d_in[8];
    float* out = (float*)d_out;

    float* ws    = (float*)d_ws;
    float* S     = ws;          // 512 floats (zeroed)
    float* bnRep = ws + 512;    // 16 x (32 sum + 32 sq) = 1024 floats (zeroed)
    float* A     = ws + 2048;   // 16384 floats

    hipMemsetAsync(d_ws, 0, 1536 * sizeof(float), stream);
    k1_parity<<<6144, 256, 0, stream>>>(x, S);
    k2_attn<<<2, 256, 0, stream>>>(S, w1l, w2l, w1h, w2h, wf, A);
    k3_main<<<1152, 192, 0, stream>>>(x, A, out, bnRep);
    k5_norm<<<6912, 256, 0, stream>>>(out, bnRep, gamma, beta);
}

// Round 7
// 469.863 us; speedup vs baseline: 1.0493x; 1.0236x over previous
//
#include <hip/hip_runtime.h>
#include <math.h>

// Problem constants
// x: (B=2, C=32, D=96, H=96, W=96) fp32
// out: (2, 32, 48, 48, 48) fp32
#define HS 0.35355339059327373f   /* 1/(2*sqrt(2)) — 3-stage Haar scale */
#define NSPAT 110592              /* 48^3 */
#define NBN   221184              /* B * 48^3 */

// ---------------------------------------------------------------------------
// K1: per-(b,c) parity sums S[b][c][p][q][r] = sum over x[2i+p][2j+q][2l+r]
// One block per (b,c,d)-plane: 96*96 floats = 2304 float4s, 256 thr * 9.
// Memory-bound (226 MB @ ~5.6 TB/s ≈ 40 µs) — near floor.
// ---------------------------------------------------------------------------
__global__ __launch_bounds__(256) void k1_parity(const float* __restrict__ x,
                                                 float* __restrict__ S) {
    int blk = blockIdx.x;            // (b*32+c)*96 + d
    int d   = blk % 96;
    int bc  = blk / 96;
    const float4* x4 = (const float4*)x + (long)blk * 2304;
    int tid = threadIdx.x;
    float aE0 = 0.f, aO0 = 0.f, aE1 = 0.f, aO1 = 0.f;  // [q][r]
#pragma unroll
    for (int i = 0; i < 9; ++i) {
        int f = tid + i * 256;           // < 2304
        float4 v = x4[f];
        int h = f / 24;                  // row within plane
        float e = v.x + v.z, o = v.y + v.w;
        if (h & 1) { aE1 += e; aO1 += o; }
        else       { aE0 += e; aO0 += o; }
    }
#pragma unroll
    for (int m = 32; m; m >>= 1) {
        aE0 += __shfl_xor(aE0, m, 64); aO0 += __shfl_xor(aO0, m, 64);
        aE1 += __shfl_xor(aE1, m, 64); aO1 += __shfl_xor(aO1, m, 64);
    }
    __shared__ float red[4][4];
    int lane = tid & 63, wave = tid >> 6;
    if (lane == 0) { red[wave][0] = aE0; red[wave][1] = aO0;
                     red[wave][2] = aE1; red[wave][3] = aO1; }
    __syncthreads();
    if (tid < 4) {
        float v = red[0][tid] + red[1][tid] + red[2][tid] + red[3][tid];
        int q = tid >> 1, r = tid & 1, p = d & 1;
        atomicAdd(&S[bc * 8 + p * 4 + q * 2 + r], v);
    }
}

// ---------------------------------------------------------------------------
// K2 (tiny): band means -> two attention MLPs -> effective fuse matrix.
// Layout: A[b][og(4)][c(32)][o'(8)][pqr(8)] — per-(og,c) slice is 64
// contiguous floats (k3 wave og reads it via scalar pipe, single-buffered).
// One block per batch b.
// ---------------------------------------------------------------------------
__global__ __launch_bounds__(256) void k2_attn(
        const float* __restrict__ S,
        const float* __restrict__ w1l, const float* __restrict__ w2l,
        const float* __restrict__ w1h, const float* __restrict__ w2h,
        const float* __restrict__ wf, float* __restrict__ A) {
    int b = blockIdx.x, tid = threadIdx.x;
    __shared__ float mlow[32], mhigh[224], h1l[2], h1h[14], ylow[32], yhigh[224];
    const float* Sb = S + b * 256;
    const float MS = HS / (float)NSPAT;   // subband mean scale
    if (tid < 32) {
        float s = 0.f;
        for (int j = 0; j < 8; ++j) s += Sb[tid * 8 + j];
        mlow[tid] = s * MS;
    }
    if (tid < 224) {
        int c = tid / 7, k = tid % 7, dm = k + 1;
        float s = 0.f;
        for (int j = 0; j < 8; ++j) {
            float sg = (__popc(j & dm) & 1) ? -1.f : 1.f;
            s += sg * Sb[c * 8 + j];
        }
        mhigh[tid] = s * MS;
    }
    __syncthreads();
    if (tid < 2) {
        float s = 0.f;
        for (int c = 0; c < 32; ++c) s += w1l[tid * 32 + c] * mlow[c];
        h1l[tid] = fmaxf(s, 0.f);
    } else if (tid < 16) {
        int j = tid - 2;
        float s = 0.f;
        for (int c = 0; c < 224; ++c) s += w1h[j * 224 + c] * mhigh[c];
        h1h[j] = fmaxf(s, 0.f);
    }
    __syncthreads();
    if (tid < 32) {
        float s = w2l[tid * 2] * h1l[0] + w2l[tid * 2 + 1] * h1l[1];
        ylow[tid] = 1.f / (1.f + expf(-s));
    } else if (tid < 256) {
        int i = tid - 32;
        float s = 0.f;
        for (int j = 0; j < 14; ++j) s += w2h[i * 14 + j] * h1h[j];
        yhigh[i] = 1.f / (1.f + expf(-s));
    }
    __syncthreads();
    for (int idx = tid; idx < 8192; idx += 256) {
        int o = idx >> 8, c = (idx >> 3) & 31, pqr = idx & 7;
        float a = wf[o * 256 + c] * ylow[c];
#pragma unroll
        for (int k = 0; k < 7; ++k) {
            float sg = (__popc(pqr & (k + 1)) & 1) ? -1.f : 1.f;
            a += sg * wf[o * 256 + 32 + c * 7 + k] * yhigh[c * 7 + k];
        }
        int og = o >> 3, op = o & 7;
        A[b * 8192 + og * 2048 + c * 64 + op * 8 + pqr] = a * HS;
    }
}

// ---------------------------------------------------------------------------
// K3 (main): z[b,o,od,oh,ow] = sum_{c,pqr} A[...] * x[b,c,2od+p,2oh+q,2ow+r]
// R7: x read ONCE from HBM (fixes R6's FETCH=445MB) while keeping the A
// footprint at 64 floats/wave/c (fixes R5's scalar serialization):
//  - Block = 4 waves over ONE 64-voxel tile; wave w computes o in [8w,8w+8)
//    over all 32 c. The 4 waves issue identical x loads -> 3 of 4 are
//    L1-hits on the SAME CU at the SAME time (R6's cross-block sharing
//    missed because siblings ran far apart; waves in a block can't).
//  - A address wave-uniform (readfirstlane) -> scalar pipe s_load_dwordx16;
//    64 floats/c single-buffered in SGPRs, 64 FMA insts to hide each batch.
//  - Per-thread: 8 acc + 8 cur + 8 prefetch x floats ≈ 40 VGPR -> 8
//    waves/SIMD cap; no LDS, no __syncthreads.
// Grid 3456 = b(2) x od(48) x vblk(36); 13824 waves = 13.5/SIMD oversub.
// BN: per-wave butterfly, lane0 atomics into 16 replica lines.
// ---------------------------------------------------------------------------
__global__ __launch_bounds__(256) void k3_main(const float* __restrict__ x,
                                               const float* __restrict__ A,
                                               float* __restrict__ z,
                                               float* __restrict__ bnRep) {
    int blk  = blockIdx.x;                 // (b*48+od)*36 + vblk
    int vblk = blk % 36;
    int tmp  = blk / 36;
    int od   = tmp % 48;
    int b    = tmp / 48;
    int tid  = threadIdx.x;
    int lane = tid & 63;
    int wv   = __builtin_amdgcn_readfirstlane(tid >> 6);  // o-group, scalar
    int v    = vblk * 64 + lane;
    int oh   = v / 48, ow = v % 48;

    const float* Ab = A + b * 8192 + wv * 2048;   // [c<32][o'<8][pqr<8], uniform

    float acc[8];
#pragma unroll
    for (int o = 0; o < 8; ++o) acc[o] = 0.f;

    const float2* x2 = (const float2*)x;
    // float2 idx: ch*442368 + d*4608 + h*48 + ow ; d=2od(+p), h=2oh(+q)
    int base = (b * 32) * 442368 + od * 9216 + oh * 96 + ow;

    float2 v00 = x2[base],        v01 = x2[base + 48];
    float2 v10 = x2[base + 4608], v11 = x2[base + 4656];
    for (int c = 0; c < 32; ++c) {
        float2 n00, n01, n10, n11;
        if (c < 31) {
            int nb = base + (c + 1) * 442368;
            n00 = x2[nb];        n01 = x2[nb + 48];
            n10 = x2[nb + 4608]; n11 = x2[nb + 4656];
        }
        const float* Ac = Ab + c * 64;
#pragma unroll
        for (int o = 0; o < 8; ++o) {
            const float* Ao = Ac + o * 8;             // uniform -> SGPRs
            acc[o] += Ao[0] * v00.x + Ao[1] * v00.y + Ao[2] * v01.x + Ao[3] * v01.y
                    + Ao[4] * v10.x + Ao[5] * v10.y + Ao[6] * v11.x + Ao[7] * v11.y;
        }
        v00 = n00; v01 = n01; v10 = n10; v11 = n11;
    }

    // z stores: per o, 64 lanes cover 64 consecutive voxels -> coalesced b32
#pragma unroll
    for (int o = 0; o < 8; ++o) {
        z[((b * 32 + wv * 8 + o) * 48 + od) * 2304 + v] = acc[o];
    }

    // BN partials: butterfly per o, lane0 atomics (16 replica lines)
    int rep = (blockIdx.x & 15) * 64;
#pragma unroll
    for (int o = 0; o < 8; ++o) {
        float sv = acc[o];
        float qv = acc[o] * acc[o];
#pragma unroll
        for (int m = 32; m; m >>= 1) {
            sv += __shfl_xor(sv, m, 64);
            qv += __shfl_xor(qv, m, 64);
        }
        if (lane == 0) {
            atomicAdd(&bnRep[rep + wv * 8 + o], sv);
            atomicAdd(&bnRep[rep + 32 + wv * 8 + o], qv);
        }
    }
}

// ---------------------------------------------------------------------------
// K5: BN finalize (sum 16 replicas, per-block recompute) + normalize + ReLU,
// in place over z (= d_out). 1769472 float4s. b_fuse cancels under BN.
// ---------------------------------------------------------------------------
__global__ __launch_bounds__(256) void k5_norm(float* __restrict__ z,
                                               const float* __restrict__ bnRep,
                                               const float* __restrict__ gamma,
                                               const float* __restrict__ beta) {
    __shared__ float s_sc[32], s_sh[32];
    int tid = threadIdx.x;
    if (tid < 32) {
        float s = 0.f, q = 0.f;
#pragma unroll
        for (int r = 0; r < 16; ++r) {
            s += bnRep[r * 64 + tid];
            q += bnRep[r * 64 + 32 + tid];
        }
        const float invN = 1.f / (float)NBN;
        float mean = s * invN;
        float var  = q * invN - mean * mean;
        float inv  = rsqrtf(var + 1e-5f);
        float sc   = gamma[tid] * inv;
        s_sc[tid] = sc;
        s_sh[tid] = beta[tid] - mean * sc;
    }
    int i = blockIdx.x * 256 + tid;                // float4 index
    float4* z4 = (float4*)z;
    float4 v = z4[i];                              // load before barrier (indep)
    __syncthreads();
    int o = (i / 27648) & 31;                      // 27648 = 48^3/4
    float sc = s_sc[o], sh = s_sh[o];
    v.x = fmaxf(v.x * sc + sh, 0.f);
    v.y = fmaxf(v.y * sc + sh, 0.f);
    v.z = fmaxf(v.z * sc + sh, 0.f);
    v.w = fmaxf(v.w * sc + sh, 0.f);
    z4[i] = v;
}

extern "C" void kernel_launch(void* const* d_in, const int* in_sizes, int n_in,
                              void* d_out, int out_size, void* d_ws, size_t ws_size,
                              hipStream_t stream) {
    const float* x    = (const float*)d_in[0];
    const float* w1l  = (const float*)d_in[1];
    const float* w2l  = (const float*)d_in[2];
    const float* w1h  = (const float*)d_in[3];
    const float* w2h  = (const float*)d_in[4];
    const float* wf   = (const float*)d_in[5];
    // d_in[6] = b_fuse: cancels exactly under training-mode BN (mean subtract)
    const float* gamma = (const float*)d_in[7];
    const float* beta  = (const float*)d_in[8];
    float* out = (float*)d_out;

    float* ws    = (float*)d_ws;
    float* S     = ws;          // 512 floats (zeroed)
    float* bnRep = ws + 512;    // 16 x (32 sum + 32 sq) = 1024 floats (zeroed)
    float* A     = ws + 2048;   // 16384 floats

    hipMemsetAsync(d_ws, 0, 1536 * sizeof(float), stream);
    k1_parity<<<6144, 256, 0, stream>>>(x, S);
    k2_attn<<<2, 256, 0, stream>>>(S, w1l, w2l, w1h, w2h, wf, A);
    k3_main<<<3456, 256, 0, stream>>>(x, A, out, bnRep);
    k5_norm<<<6912, 256, 0, stream>>>(out, bnRep, gamma, beta);
}